// Round 5
// baseline (342.911 us; speedup 1.0000x reference)
//
#include <hip/hip_runtime.h>

typedef __attribute__((ext_vector_type(8))) short short8;
typedef __attribute__((ext_vector_type(4))) short short4v;
typedef __attribute__((ext_vector_type(4))) float float4v;

typedef const __attribute__((address_space(1))) unsigned int* gptr_t;
typedef __attribute__((address_space(3))) unsigned int* lptr_t;

__device__ __forceinline__ unsigned short f2bf(float f) {
  unsigned u = __float_as_uint(f);
  u += 0x7FFFu + ((u >> 16) & 1u);
  return (unsigned short)(u >> 16);
}
__device__ __forceinline__ float bf2f(unsigned short h) {
  return __uint_as_float(((unsigned)h) << 16);
}

// ---------------- f32 -> bf16 conversion (vectorized) ----------------
__global__ __launch_bounds__(256) void cvt_bf16_kernel(const float* __restrict__ in,
                                                       unsigned short* __restrict__ out,
                                                       int n4) {
  int i = blockIdx.x * 256 + threadIdx.x;
  if (i >= n4) return;
  float4v v = ((const float4v*)in)[i];
  short4v o;
  o[0] = (short)f2bf(v[0]);
  o[1] = (short)f2bf(v[1]);
  o[2] = (short)f2bf(v[2]);
  o[3] = (short)f2bf(v[3]);
  ((short4v*)out)[i] = o;
}

// ---------------- pad-mask compaction: prefix counts + index map (+ zero mean_x) ----------------
__global__ __launch_bounds__(256) void compact_kernel(const int* __restrict__ pad,
                                                      int* __restrict__ jmap,
                                                      int* __restrict__ cntb,
                                                      float* __restrict__ mean_x) {
  int b = blockIdx.x;
  const int* prow = pad + b * 2048;
  int t = threadIdx.x;
  float4v z = {0.f, 0.f, 0.f, 0.f};
  ((float4v*)(mean_x + b * 1024))[t] = z;
  int base = t * 8;
  int ind[8], incl[8];
  int s = 0;
#pragma unroll
  for (int e = 0; e < 8; ++e) {
    ind[e] = (prow[base + e] == 0);
    s += ind[e];
    incl[e] = s;
  }
  int lane = t & 63, wv = t >> 6;
  int v = s;
#pragma unroll
  for (int off = 1; off < 64; off <<= 1) {
    int u = __shfl_up(v, off);
    if (lane >= off) v += u;
  }
  __shared__ int wsum[4];
  if (lane == 63) wsum[wv] = v;
  __syncthreads();
  int wbase = 0;
  for (int w = 0; w < wv; ++w) wbase += wsum[w];
  int excl_base = wbase + v - s;
#pragma unroll
  for (int e = 0; e < 8; ++e) {
    int cnt_i = excl_base + incl[e];
    cntb[b * 2048 + base + e] = cnt_i;
    if (ind[e]) jmap[b * 2048 + cnt_i - 1] = base + e;
  }
}

// ---------------- gather compacted x rows (zero-pad to 128-row boundary) ----------------
__global__ __launch_bounds__(256) void gatherX_kernel(const unsigned short* __restrict__ xb,
                                                      const int* __restrict__ jmap,
                                                      const int* __restrict__ cntb,
                                                      unsigned short* __restrict__ xc) {
  int jc = blockIdx.x, b = blockIdx.y;
  int Nc = cntb[b * 2048 + 2047];
  int W = (Nc + 127) & ~127;
  if (jc >= W) return;
  short4v* dst = (short4v*)(xc + ((size_t)(b * 2048 + jc)) * 1024);
  if (jc < Nc) {
    int j = jmap[b * 2048 + jc];
    const short4v* src = (const short4v*)(xb + ((size_t)(b * 2048 + j)) * 1024);
    dst[threadIdx.x] = src[threadIdx.x];
  } else {
    short4v z = {0, 0, 0, 0};
    dst[threadIdx.x] = z;
  }
}

// ---------------- column-sum of xb per batch (for degenerate-row fixup) ----------------
__global__ __launch_bounds__(256) void meanx_kernel(const unsigned short* __restrict__ xb,
                                                    float* __restrict__ mean_x) {
  int b = blockIdx.x, hblk = blockIdx.y, iblk = blockIdx.z;
  int h = hblk * 256 + threadIdx.x;
  float s = 0.f;
  const unsigned short* base = xb + ((size_t)b * 2048 + (size_t)iblk * 256) * 1024 + h;
  for (int i = 0; i < 256; ++i) s += bf2f(base[(size_t)i * 1024]);
  atomicAdd(&mean_x[b * 1024 + h], s);
}

// ---------------- fixmean = mean_x/2048 @ Wv^T + bv ----------------
__global__ __launch_bounds__(256) void gemv_kernel(const float* __restrict__ mean_x,
                                                   const unsigned short* __restrict__ wv,
                                                   const float* __restrict__ bv,
                                                   float* __restrict__ fixmean) {
  int b = blockIdx.x, dblk = blockIdx.y;
  int d = dblk * 256 + threadIdx.x;
  const unsigned short* wrow = wv + (size_t)d * 1024;
  const float* mx = mean_x + b * 1024;
  float s = 0.f;
  for (int h = 0; h < 1024; h += 8) {
    short8 w = *(const short8*)(wrow + h);
#pragma unroll
    for (int e = 0; e < 8; ++e) s += mx[h + e] * bf2f(((const unsigned short*)&w)[e]);
  }
  fixmean[b * 1024 + d] = s * (1.0f / 2048.0f) + bv[d];
}

// ---------------- generic bf16 GEMM, C = A @ B^T (2-phase double-buffered) ----------------
// MODE 0: proj-q   : bf16 out + bias1, XCD-swizzled grid (8,128)
// MODE 1: proj-kv  : per-batch, M-tile early-exit at Nc; n<1024 -> kc (+bias1),
//                    n>=1024 -> vtc[(bz<<21)|(nn<<11)|m] (+bias2); swizzled grid (16,16,8)
// MODE 2: qk       : bf16 out, compacted-causal tile-skip
// MODE 3: pv       : f32 out, K-limit roundup64(cnt)
template <int MODE>
__global__ __launch_bounds__(256, 2) void gemm_bt_kernel(
    const unsigned short* __restrict__ A, const unsigned short* __restrict__ B,
    const float* __restrict__ bias1, const float* __restrict__ bias2,
    void* __restrict__ C, unsigned short* __restrict__ C2, const int* __restrict__ cnt,
    int K, int lda, int ldb, int ldc, size_t sA, size_t sB, size_t sC) {
  int bx = blockIdx.x, by = blockIdx.y, bz = blockIdx.z;
  if (MODE == 0) {  // nwg=1024 (8x128), bijective XCD swizzle
    int wg = by * 8 + bx;
    int s = (wg & 7) * 128 + (wg >> 3);
    bx = s & 7;
    by = s >> 3;
  }
  if (MODE == 1) {  // nwg=256 (16x16) per batch
    int wg = by * 16 + bx;
    int s = (wg & 7) * 32 + (wg >> 3);
    bx = s & 15;
    by = s >> 4;
  }
  int Kend = K;
  if (MODE == 1) {
    int Nc = cnt[(bz << 11) + 2047];
    if (by * 128 >= Nc) return;
  }
  if (MODE == 2) {
    int tc = cnt[(bz << 11) + (by * 128 + 127)];
    if (bx * 128 >= tc) return;
  }
  if (MODE == 3) {
    int tc = cnt[(bz << 11) + (by * 128 + 127)];
    Kend = (tc + 63) & ~63;
  }

  // two 32KB buffers: buf p at lds + p*32768 (A: +0, B: +16384)
  __shared__ __align__(16) char lds[65536];

  int tid = threadIdx.x;
  int wave = tid >> 6, lane = tid & 63;
  int lm = lane & 15, g = lane >> 4;
  int wm = wave >> 1, wn = wave & 1;
  int swl = (lm & 7) << 4;

  float4v acc[4][4];
#pragma unroll
  for (int i = 0; i < 4; ++i)
#pragma unroll
    for (int j = 0; j < 4; ++j) {
      float4v z = {0.f, 0.f, 0.f, 0.f};
      acc[i][j] = z;
    }

  const char* Abase = (const char*)(A + sA * (size_t)bz + (size_t)(by * 128) * (size_t)lda);
  const char* Bbase = (const char*)(B + sB * (size_t)bz + (size_t)(bx * 128) * (size_t)ldb);
  size_t strideA = (size_t)lda * 2u;
  size_t strideB = (size_t)ldb * 2u;

  int Lbase = wave * 1024 + lane * 16;

  auto STAGE = [&](int p, int kt) {
#pragma unroll
    for (int c = 0; c < 4; ++c) {
      int L = c * 4096 + Lbase;
      int row = L >> 7;
      int lb = (L & 127) ^ ((row & 7) << 4);  // inverse-swizzled source byte within row
      const char* ga = Abase + (size_t)row * strideA + (size_t)(kt * 2) + lb;
      __builtin_amdgcn_global_load_lds(
          (gptr_t)(const void*)ga,
          (lptr_t)(void*)(lds + p * 32768 + c * 4096 + wave * 1024), 16, 0, 0);
      const char* gb = Bbase + (size_t)row * strideB + (size_t)(kt * 2) + lb;
      __builtin_amdgcn_global_load_lds(
          (gptr_t)(const void*)gb,
          (lptr_t)(void*)(lds + p * 32768 + 16384 + c * 4096 + wave * 1024), 16, 0, 0);
    }
  };

  int nt = Kend >> 6;
  STAGE(0, 0);
  __syncthreads();  // compiler emits vmcnt(0): buf0 ready
  int cur = 0;
  for (int t = 0; t < nt; ++t) {
    if (t + 1 < nt) STAGE(cur ^ 1, (t + 1) * 64);  // prefetch flies under MFMA phase
    const char* lA = lds + cur * 32768;
    const char* lB = lA + 16384;
#pragma unroll
    for (int k0 = 0; k0 < 64; k0 += 32) {
      short8 af[4], bfv[4];
      int b0 = (k0 * 2 + 16 * g) ^ swl;  // contiguous 16B k-chunk (self-consistent permutation)
#pragma unroll
      for (int mi = 0; mi < 4; ++mi) {
        const char* p = lA + (wm * 64 + mi * 16 + lm) * 128;
        af[mi] = *(const short8*)(p + b0);
      }
#pragma unroll
      for (int ni = 0; ni < 4; ++ni) {
        const char* p = lB + (wn * 64 + ni * 16 + lm) * 128;
        bfv[ni] = *(const short8*)(p + b0);
      }
#pragma unroll
      for (int mi = 0; mi < 4; ++mi)
#pragma unroll
        for (int ni = 0; ni < 4; ++ni)
          acc[mi][ni] =
              __builtin_amdgcn_mfma_f32_16x16x32_bf16(af[mi], bfv[ni], acc[mi][ni], 0, 0, 0);
    }
    __syncthreads();  // drains residual vmcnt (next buf) + all waves done reading cur
    cur ^= 1;
  }

  // epilogue: C/D layout col = lane&15, row = (lane>>4)*4 + r
  int mb = by * 128 + wm * 64 + g * 4;
  int nb = bx * 128 + wn * 64 + lm;
#pragma unroll
  for (int mi = 0; mi < 4; ++mi) {
#pragma unroll
    for (int ni = 0; ni < 4; ++ni) {
      int n = nb + ni * 16;
      float bias = 0.0f;
      if (MODE == 0) bias = bias1[n];
      if (MODE == 1) {
        int nn = n & 1023;
        bias = (n < 1024) ? bias1[nn] : bias2[nn];
      }
#pragma unroll
      for (int r = 0; r < 4; ++r) {
        int m = mb + mi * 16 + r;
        float v = acc[mi][ni][r] + bias;
        if (MODE == 0) {
          ((unsigned short*)C)[(size_t)m * (size_t)ldc + n] = f2bf(v);
        } else if (MODE == 1) {
          if (n < 1024) {
            ((unsigned short*)C)[sC * (size_t)bz + (size_t)m * 1024u + n] = f2bf(v);
          } else {
            size_t idx = ((size_t)bz << 21) + ((size_t)(n - 1024) << 11) + (size_t)m;
            C2[idx] = f2bf(v);
          }
        } else if (MODE == 2) {
          ((unsigned short*)C)[sC * (size_t)bz + (size_t)m * (size_t)ldc + n] = f2bf(v);
        } else {
          ((float*)C)[sC * (size_t)bz + (size_t)m * (size_t)ldc + n] = v;
        }
      }
    }
  }
}

// ---------------- compacted masked softmax, in-place on bf16 scores ----------------
__global__ __launch_bounds__(256) void softmax_kernel(unsigned short* __restrict__ sp,
                                                      const int* __restrict__ cntb) {
  int i = blockIdx.x, b = blockIdx.y;
  int cnt_i = cntb[b * 2048 + i];
  int tcnt = cntb[b * 2048 + (i | 127)];
  int W = (tcnt + 127) & ~127;
  unsigned short* row = sp + ((size_t)b * 2048 + (size_t)i) * 2048;
  int tid = threadIdx.x;
  int j0 = tid * 8;
  bool active = (j0 < W);

  float t[8];
  if (active) {
    short8 sv = *(const short8*)(row + j0);
#pragma unroll
    for (int e = 0; e < 8; ++e) {
      int jc = j0 + e;
      bool msk = (jc >= cnt_i);
      float raw = bf2f(((const unsigned short*)&sv)[e]);
      t[e] = (msk ? -1e10f : raw) * 0.03125f;
    }
  } else {
#pragma unroll
    for (int e = 0; e < 8; ++e) t[e] = -1e10f * 0.03125f;
  }

  float m = t[0];
#pragma unroll
  for (int e = 1; e < 8; ++e) m = fmaxf(m, t[e]);
#pragma unroll
  for (int o = 32; o > 0; o >>= 1) m = fmaxf(m, __shfl_xor(m, o));
  __shared__ float redm[4], reds[4];
  int wv = tid >> 6, ln = tid & 63;
  if (ln == 0) redm[wv] = m;
  __syncthreads();
  m = fmaxf(fmaxf(redm[0], redm[1]), fmaxf(redm[2], redm[3]));

  float p[8];
  float s = 0.f;
#pragma unroll
  for (int e = 0; e < 8; ++e) {
    p[e] = __expf(t[e] - m);
    s += p[e];
  }
#pragma unroll
  for (int o = 32; o > 0; o >>= 1) s += __shfl_xor(s, o);
  if (ln == 0) reds[wv] = s;
  __syncthreads();
  s = reds[0] + reds[1] + reds[2] + reds[3];
  float inv = 1.0f / s;

  if (active) {
    short8 ov;
#pragma unroll
    for (int e = 0; e < 8; ++e) ((unsigned short*)&ov)[e] = (short)f2bf(p[e] * inv);
    *(short8*)(row + j0) = ov;
  }
}

// ---------------- degenerate-row fixup apply ----------------
__global__ __launch_bounds__(256) void fixup_apply_kernel(const int* __restrict__ cntb,
                                                          const float* __restrict__ fixmean,
                                                          float* __restrict__ out) {
  int b = blockIdx.x, dchunk = blockIdx.y;
  int d = dchunk * 256 + threadIdx.x;
  float val = fixmean[b * 1024 + d];
  for (int i = 0; i < 2048; ++i) {
    if (cntb[b * 2048 + i] != 0) break;
    out[((size_t)b * 2048 + (size_t)i) * 1024 + d] = val;
  }
}

// ---------------- launch ----------------
extern "C" void kernel_launch(void* const* d_in, const int* in_sizes, int n_in,
                              void* d_out, int out_size, void* d_ws, size_t ws_size,
                              hipStream_t stream) {
  const float* x = (const float*)d_in[0];
  const int* pad = (const int*)d_in[1];
  const float* Wq = (const float*)d_in[2];
  const float* bq = (const float*)d_in[3];
  const float* Wk = (const float*)d_in[4];
  const float* bk = (const float*)d_in[5];
  const float* Wv = (const float*)d_in[6];
  const float* bv = (const float*)d_in[7];
  float* out = (float*)d_out;

  char* ws = (char*)d_ws;
  unsigned short* xb  = (unsigned short*)(ws + 0);           // 32MB [16384,1024]; dead after proj-q
  unsigned short* kc  = (unsigned short*)(ws + 0);           // 32MB [8,2048,1024] (reuse xb)
  unsigned short* xc  = (unsigned short*)(ws + 33554432);    // 32MB [8,2048,1024]
  unsigned short* wb  = (unsigned short*)(ws + 67108864);    // 6MB  [3072,1024] = Wq;Wk;Wv
  int*   jmap    = (int*)(ws + 73400320);                    // 64KB
  int*   cntb    = (int*)(ws + 73465856);                    // 64KB
  float* mean_x  = (float*)(ws + 73531392);                  // 32KB
  float* fixmean = (float*)(ws + 73564160);                  // 32KB
  unsigned short* qb  = (unsigned short*)(ws + 75497472);    // 32MB [16384,1024]
  unsigned short* vtc = (unsigned short*)(ws + 109051904);   // 32MB [8,1024,2048]
  unsigned short* sp  = (unsigned short*)(ws + 142606336);   // 64MB [8,2048,2048]

  // converts
  cvt_bf16_kernel<<<16384, 256, 0, stream>>>(x, xb, 4194304);
  cvt_bf16_kernel<<<1024, 256, 0, stream>>>(Wq, wb, 262144);
  cvt_bf16_kernel<<<1024, 256, 0, stream>>>(Wk, wb + 1048576, 262144);
  cvt_bf16_kernel<<<1024, 256, 0, stream>>>(Wv, wb + 2097152, 262144);

  // pad compaction + x gather + column-sum
  compact_kernel<<<8, 256, 0, stream>>>(pad, jmap, cntb, mean_x);
  dim3 gx(2048, 8);
  gatherX_kernel<<<gx, 256, 0, stream>>>(xb, jmap, cntb, xc);
  dim3 gmx(8, 4, 8);
  meanx_kernel<<<gmx, 256, 0, stream>>>(xb, mean_x);

  // proj-q: q = x@Wq^T + bq  [16384,1024]
  dim3 g1(8, 128, 1);
  gemm_bt_kernel<0><<<g1, 256, 0, stream>>>(xb, wb, bq, nullptr, qb, nullptr, nullptr,
                                            1024, 1024, 1024, 1024, 0, 0, 0);

  // proj-kv: [kc | vT] from compacted xc (per batch, early-exit at Nc); kc overlays dead xb
  dim3 g2(16, 16, 8);
  gemm_bt_kernel<1><<<g2, 256, 0, stream>>>(xc, wb + 1048576, bk, bv, kc, vtc, cntb,
                                            1024, 1024, 1024, 1024, 2097152, 0, 2097152);

  // fixmean GEMV (needs wb alive)
  dim3 g3(8, 4);
  gemv_kernel<<<g3, 256, 0, stream>>>(mean_x, wb + 2097152, bv, fixmean);

  // scores[b] = q_b @ kc_b^T (compacted-causal tile-skip)
  dim3 g4(16, 16, 8);
  gemm_bt_kernel<2><<<g4, 256, 0, stream>>>(qb, kc, nullptr, nullptr, sp, nullptr, cntb,
                                            1024, 1024, 1024, 2048, 2097152, 2097152, 4194304);

  // compacted masked softmax (in place)
  dim3 g5(2048, 8);
  softmax_kernel<<<g5, 256, 0, stream>>>(sp, cntb);

  // out[b] = P_b @ Vc_b (K-limit roundup64(cnt))
  dim3 g6(8, 16, 8);
  gemm_bt_kernel<3><<<g6, 256, 0, stream>>>(sp, vtc, nullptr, nullptr, out, nullptr, cntb,
                                            2048, 2048, 2048, 1024, 4194304, 2097152, 2097152);

  // degenerate (fully-masked) rows
  fixup_apply_kernel<<<g3, 256, 0, stream>>>(cntb, fixmean, out);
}

// Round 6
// 300.726 us; speedup vs baseline: 1.1403x; 1.1403x over previous
//
#include <hip/hip_runtime.h>

typedef __attribute__((ext_vector_type(8))) short short8;
typedef __attribute__((ext_vector_type(4))) short short4v;
typedef __attribute__((ext_vector_type(4))) float float4v;

typedef const __attribute__((address_space(1))) unsigned int* gptr_t;
typedef __attribute__((address_space(3))) unsigned int* lptr_t;

__device__ __forceinline__ unsigned short f2bf(float f) {
  unsigned u = __float_as_uint(f);
  u += 0x7FFFu + ((u >> 16) & 1u);
  return (unsigned short)(u >> 16);
}
__device__ __forceinline__ float bf2f(unsigned short h) {
  return __uint_as_float(((unsigned)h) << 16);
}

// ---------------- f32 -> bf16 conversion (vectorized) ----------------
__global__ __launch_bounds__(256) void cvt_bf16_kernel(const float* __restrict__ in,
                                                       unsigned short* __restrict__ out,
                                                       int n4) {
  int i = blockIdx.x * 256 + threadIdx.x;
  if (i >= n4) return;
  float4v v = ((const float4v*)in)[i];
  short4v o;
  o[0] = (short)f2bf(v[0]);
  o[1] = (short)f2bf(v[1]);
  o[2] = (short)f2bf(v[2]);
  o[3] = (short)f2bf(v[3]);
  ((short4v*)out)[i] = o;
}

// ---------------- pad-mask compaction: prefix counts + index map (+ zero mean_x) ----------------
__global__ __launch_bounds__(256) void compact_kernel(const int* __restrict__ pad,
                                                      int* __restrict__ jmap,
                                                      int* __restrict__ cntb,
                                                      float* __restrict__ mean_x) {
  int b = blockIdx.x;
  const int* prow = pad + b * 2048;
  int t = threadIdx.x;
  float4v z = {0.f, 0.f, 0.f, 0.f};
  ((float4v*)(mean_x + b * 1024))[t] = z;
  int base = t * 8;
  int ind[8], incl[8];
  int s = 0;
#pragma unroll
  for (int e = 0; e < 8; ++e) {
    ind[e] = (prow[base + e] == 0);
    s += ind[e];
    incl[e] = s;
  }
  int lane = t & 63, wv = t >> 6;
  int v = s;
#pragma unroll
  for (int off = 1; off < 64; off <<= 1) {
    int u = __shfl_up(v, off);
    if (lane >= off) v += u;
  }
  __shared__ int wsum[4];
  if (lane == 63) wsum[wv] = v;
  __syncthreads();
  int wbase = 0;
  for (int w = 0; w < wv; ++w) wbase += wsum[w];
  int excl_base = wbase + v - s;
#pragma unroll
  for (int e = 0; e < 8; ++e) {
    int cnt_i = excl_base + incl[e];
    cntb[b * 2048 + base + e] = cnt_i;
    if (ind[e]) jmap[b * 2048 + cnt_i - 1] = base + e;
  }
}

// ---------------- gather compacted x rows (zero-pad to 128-row boundary) ----------------
__global__ __launch_bounds__(256) void gatherX_kernel(const unsigned short* __restrict__ xb,
                                                      const int* __restrict__ jmap,
                                                      const int* __restrict__ cntb,
                                                      unsigned short* __restrict__ xc) {
  int jc = blockIdx.x, b = blockIdx.y;
  int Nc = cntb[b * 2048 + 2047];
  int W = (Nc + 127) & ~127;
  if (jc >= W) return;
  short4v* dst = (short4v*)(xc + ((size_t)(b * 2048 + jc)) * 1024);
  if (jc < Nc) {
    int j = jmap[b * 2048 + jc];
    const short4v* src = (const short4v*)(xb + ((size_t)(b * 2048 + j)) * 1024);
    dst[threadIdx.x] = src[threadIdx.x];
  } else {
    short4v z = {0, 0, 0, 0};
    dst[threadIdx.x] = z;
  }
}

// ---------------- column-sum of xb per batch (for degenerate-row fixup) ----------------
__global__ __launch_bounds__(256) void meanx_kernel(const unsigned short* __restrict__ xb,
                                                    float* __restrict__ mean_x) {
  int b = blockIdx.x, hblk = blockIdx.y, iblk = blockIdx.z;
  int h = hblk * 256 + threadIdx.x;
  float s = 0.f;
  const unsigned short* base = xb + ((size_t)b * 2048 + (size_t)iblk * 256) * 1024 + h;
  for (int i = 0; i < 256; ++i) s += bf2f(base[(size_t)i * 1024]);
  atomicAdd(&mean_x[b * 1024 + h], s);
}

// ---------------- fixmean = mean_x/2048 @ Wv^T + bv ----------------
__global__ __launch_bounds__(256) void gemv_kernel(const float* __restrict__ mean_x,
                                                   const unsigned short* __restrict__ wv,
                                                   const float* __restrict__ bv,
                                                   float* __restrict__ fixmean) {
  int b = blockIdx.x, dblk = blockIdx.y;
  int d = dblk * 256 + threadIdx.x;
  const unsigned short* wrow = wv + (size_t)d * 1024;
  const float* mx = mean_x + b * 1024;
  float s = 0.f;
  for (int h = 0; h < 1024; h += 8) {
    short8 w = *(const short8*)(wrow + h);
#pragma unroll
    for (int e = 0; e < 8; ++e) s += mx[h + e] * bf2f(((const unsigned short*)&w)[e]);
  }
  fixmean[b * 1024 + d] = s * (1.0f / 2048.0f) + bv[d];
}

// ---------------- generic bf16 GEMM, C = A @ B^T (single-buffered, round-4 structure) ----------------
// MODE 0: fused projection q|k|v. Grid (24,128), XCD-swizzled.
//         bx<8: q from A=xb (all rows) -> C (qb, dense [16384,1024]) + b1
//         bx in 8..15: k from A2=xc (compacted, early-exit) -> C3 (kc dense) + b2
//         bx in 16..23: v from A2=xc -> C2 vtc[(b<<21)|(nn<<11)|jc] + b3
// MODE 1: qk  : bf16 out, compacted-causal tile-skip (per-batch bz)
// MODE 2: pv  : f32 out, K-limit roundup64(cnt) (per-batch bz)
template <int MODE>
__global__ __launch_bounds__(256, 4) void gemm_bt_kernel(
    const unsigned short* __restrict__ A, const unsigned short* __restrict__ A2,
    const unsigned short* __restrict__ B,
    const float* __restrict__ b1, const float* __restrict__ b2, const float* __restrict__ b3,
    void* __restrict__ C, unsigned short* __restrict__ C2, unsigned short* __restrict__ C3,
    const int* __restrict__ cnt,
    int K, int lda, int ldb, int ldc, size_t sA, size_t sB, size_t sC) {
  int bx = blockIdx.x, by = blockIdx.y, bz = blockIdx.z;
  const unsigned short* Aptr = A;
  if (MODE == 0) {  // nwg = 24*128 = 3072, bijective XCD swizzle
    int wg = by * 24 + bx;
    int s = (wg & 7) * 384 + (wg >> 3);
    bx = s % 24;
    by = s / 24;
    int r = bx >> 3;
    if (r > 0) {
      int b = by >> 4;
      if (((by & 15) << 7) >= cnt[(b << 11) + 2047]) return;
      Aptr = A2;
    }
  }
  int Kend = K;
  if (MODE == 1) {
    int tc = cnt[(bz << 11) + (by * 128 + 127)];
    if (bx * 128 >= tc) return;
  }
  if (MODE == 2) {
    int tc = cnt[(bz << 11) + (by * 128 + 127)];
    Kend = (tc + 63) & ~63;
  }

  __shared__ __align__(16) char lds[32768];
  char* ldsA = lds;
  char* ldsB = lds + 16384;

  int tid = threadIdx.x;
  int wave = tid >> 6, lane = tid & 63;
  int lm = lane & 15, g = lane >> 4;
  int wm = wave >> 1, wn = wave & 1;
  int swl = (lm & 7) << 4;

  float4v acc[4][4];
#pragma unroll
  for (int i = 0; i < 4; ++i)
#pragma unroll
    for (int j = 0; j < 4; ++j) {
      float4v z = {0.f, 0.f, 0.f, 0.f};
      acc[i][j] = z;
    }

  const char* Abase = (const char*)(Aptr + sA * (size_t)bz + (size_t)(by * 128) * (size_t)lda);
  const char* Bbase = (const char*)(B + sB * (size_t)bz + (size_t)(bx * 128) * (size_t)ldb);
  size_t strideA = (size_t)lda * 2u;
  size_t strideB = (size_t)ldb * 2u;

  int Lbase = wave * 1024 + lane * 16;

  for (int kt = 0; kt < Kend; kt += 64) {
#pragma unroll
    for (int c = 0; c < 4; ++c) {
      int L = c * 4096 + Lbase;
      int row = L >> 7;
      int lb = (L & 127) ^ ((row & 7) << 4);  // inverse-swizzled source byte within row
      const char* ga = Abase + (size_t)row * strideA + (size_t)(kt * 2) + lb;
      __builtin_amdgcn_global_load_lds((gptr_t)(const void*)ga,
                                       (lptr_t)(void*)(ldsA + c * 4096 + wave * 1024), 16, 0, 0);
      const char* gb = Bbase + (size_t)row * strideB + (size_t)(kt * 2) + lb;
      __builtin_amdgcn_global_load_lds((gptr_t)(const void*)gb,
                                       (lptr_t)(void*)(ldsB + c * 4096 + wave * 1024), 16, 0, 0);
    }
    __syncthreads();

#pragma unroll
    for (int k0 = 0; k0 < 64; k0 += 32) {
      short8 af[4], bfv[4];
      int b0 = (k0 * 2 + 16 * g) ^ swl;  // contiguous 16B k-chunk (self-consistent permutation)
#pragma unroll
      for (int mi = 0; mi < 4; ++mi) {
        const char* p = ldsA + (wm * 64 + mi * 16 + lm) * 128;
        af[mi] = *(const short8*)(p + b0);
      }
#pragma unroll
      for (int ni = 0; ni < 4; ++ni) {
        const char* p = ldsB + (wn * 64 + ni * 16 + lm) * 128;
        bfv[ni] = *(const short8*)(p + b0);
      }
#pragma unroll
      for (int mi = 0; mi < 4; ++mi)
#pragma unroll
        for (int ni = 0; ni < 4; ++ni)
          acc[mi][ni] =
              __builtin_amdgcn_mfma_f32_16x16x32_bf16(af[mi], bfv[ni], acc[mi][ni], 0, 0, 0);
    }
    __syncthreads();
  }

  // epilogue: C/D layout col = lane&15, row = (lane>>4)*4 + r   [m89-verified]
  int mb = by * 128 + wm * 64 + g * 4;
  int nb = bx * 128 + wn * 64 + lm;
#pragma unroll
  for (int mi = 0; mi < 4; ++mi) {
#pragma unroll
    for (int ni = 0; ni < 4; ++ni) {
      int n = nb + ni * 16;
      float bias = 0.0f;
      if (MODE == 0) {
        int nn = n & 1023;
        int r = n >> 10;
        bias = (r == 0) ? b1[nn] : ((r == 1) ? b2[nn] : b3[nn]);
      }
#pragma unroll
      for (int r4 = 0; r4 < 4; ++r4) {
        int m = mb + mi * 16 + r4;
        float v = acc[mi][ni][r4] + bias;
        if (MODE == 0) {
          int nn = n & 1023;
          int r = n >> 10;
          if (r == 0) {
            ((unsigned short*)C)[(size_t)m * 1024u + nn] = f2bf(v);
          } else if (r == 1) {
            C3[(size_t)m * 1024u + nn] = f2bf(v);
          } else {
            size_t idx = ((size_t)(m >> 11) << 21) + ((size_t)nn << 11) + (size_t)(m & 2047);
            C2[idx] = f2bf(v);
          }
        } else if (MODE == 1) {
          ((unsigned short*)C)[sC * (size_t)bz + (size_t)m * (size_t)ldc + n] = f2bf(v);
        } else {
          ((float*)C)[sC * (size_t)bz + (size_t)m * (size_t)ldc + n] = v;
        }
      }
    }
  }
}

// ---------------- compacted masked softmax, in-place on bf16 scores ----------------
__global__ __launch_bounds__(256) void softmax_kernel(unsigned short* __restrict__ sp,
                                                      const int* __restrict__ cntb) {
  int i = blockIdx.x, b = blockIdx.y;
  int cnt_i = cntb[b * 2048 + i];
  int tcnt = cntb[b * 2048 + (i | 127)];
  int W = (tcnt + 127) & ~127;
  unsigned short* row = sp + ((size_t)b * 2048 + (size_t)i) * 2048;
  int tid = threadIdx.x;
  int j0 = tid * 8;
  bool active = (j0 < W);

  float t[8];
  if (active) {
    short8 sv = *(const short8*)(row + j0);
#pragma unroll
    for (int e = 0; e < 8; ++e) {
      int jc = j0 + e;
      bool msk = (jc >= cnt_i);
      float raw = bf2f(((const unsigned short*)&sv)[e]);
      t[e] = (msk ? -1e10f : raw) * 0.03125f;
    }
  } else {
#pragma unroll
    for (int e = 0; e < 8; ++e) t[e] = -1e10f * 0.03125f;
  }

  float m = t[0];
#pragma unroll
  for (int e = 1; e < 8; ++e) m = fmaxf(m, t[e]);
#pragma unroll
  for (int o = 32; o > 0; o >>= 1) m = fmaxf(m, __shfl_xor(m, o));
  __shared__ float redm[4], reds[4];
  int wv = tid >> 6, ln = tid & 63;
  if (ln == 0) redm[wv] = m;
  __syncthreads();
  m = fmaxf(fmaxf(redm[0], redm[1]), fmaxf(redm[2], redm[3]));

  float p[8];
  float s = 0.f;
#pragma unroll
  for (int e = 0; e < 8; ++e) {
    p[e] = __expf(t[e] - m);
    s += p[e];
  }
#pragma unroll
  for (int o = 32; o > 0; o >>= 1) s += __shfl_xor(s, o);
  if (ln == 0) reds[wv] = s;
  __syncthreads();
  s = reds[0] + reds[1] + reds[2] + reds[3];
  float inv = 1.0f / s;

  if (active) {
    short8 ov;
#pragma unroll
    for (int e = 0; e < 8; ++e) ((unsigned short*)&ov)[e] = (short)f2bf(p[e] * inv);
    *(short8*)(row + j0) = ov;
  }
}

// ---------------- degenerate-row fixup apply ----------------
__global__ __launch_bounds__(256) void fixup_apply_kernel(const int* __restrict__ cntb,
                                                          const float* __restrict__ fixmean,
                                                          float* __restrict__ out) {
  int b = blockIdx.x, dchunk = blockIdx.y;
  int d = dchunk * 256 + threadIdx.x;
  float val = fixmean[b * 1024 + d];
  for (int i = 0; i < 2048; ++i) {
    if (cntb[b * 2048 + i] != 0) break;
    out[((size_t)b * 2048 + (size_t)i) * 1024 + d] = val;
  }
}

// ---------------- launch ----------------
extern "C" void kernel_launch(void* const* d_in, const int* in_sizes, int n_in,
                              void* d_out, int out_size, void* d_ws, size_t ws_size,
                              hipStream_t stream) {
  const float* x = (const float*)d_in[0];
  const int* pad = (const int*)d_in[1];
  const float* Wq = (const float*)d_in[2];
  const float* bq = (const float*)d_in[3];
  const float* Wk = (const float*)d_in[4];
  const float* bk = (const float*)d_in[5];
  const float* Wv = (const float*)d_in[6];
  const float* bv = (const float*)d_in[7];
  float* out = (float*)d_out;

  char* ws = (char*)d_ws;
  unsigned short* xb  = (unsigned short*)(ws + 0);           // 32MB [16384,1024]; dead after proj
  unsigned short* kc  = (unsigned short*)(ws + 0);           // -- kc goes to its own region below
  unsigned short* xc  = (unsigned short*)(ws + 33554432);    // 32MB [8,2048,1024]
  unsigned short* wb  = (unsigned short*)(ws + 67108864);    // 6MB  [3072,1024] = Wq;Wk;Wv
  int*   jmap    = (int*)(ws + 73400320);                    // 64KB
  int*   cntb    = (int*)(ws + 73465856);                    // 64KB
  float* mean_x  = (float*)(ws + 73531392);                  // 32KB
  float* fixmean = (float*)(ws + 73564160);                  // 32KB
  unsigned short* qb  = (unsigned short*)(ws + 75497472);    // 32MB [16384,1024]
  unsigned short* vtc = (unsigned short*)(ws + 109051904);   // 32MB [8,1024,2048]
  unsigned short* sp  = (unsigned short*)(ws + 142606336);   // 64MB [8,2048,2048]
  unsigned short* kcb = (unsigned short*)(ws + 209715200);   // 32MB [8,2048,1024]

  // converts
  cvt_bf16_kernel<<<16384, 256, 0, stream>>>(x, xb, 4194304);
  cvt_bf16_kernel<<<1024, 256, 0, stream>>>(Wq, wb, 262144);
  cvt_bf16_kernel<<<1024, 256, 0, stream>>>(Wk, wb + 1048576, 262144);
  cvt_bf16_kernel<<<1024, 256, 0, stream>>>(Wv, wb + 2097152, 262144);

  // pad compaction + x gather + column-sum
  compact_kernel<<<8, 256, 0, stream>>>(pad, jmap, cntb, mean_x);
  dim3 gx(2048, 8);
  gatherX_kernel<<<gx, 256, 0, stream>>>(xb, jmap, cntb, xc);
  dim3 gmx(8, 4, 8);
  meanx_kernel<<<gmx, 256, 0, stream>>>(xb, mean_x);

  // fused projection: q (from xb) | k,v (from xc, compacted) — one 3072-block dispatch
  dim3 g1(24, 128, 1);
  gemm_bt_kernel<0><<<g1, 256, 0, stream>>>(xb, xc, wb, bq, bk, bv, qb, vtc, kcb, cntb,
                                            1024, 1024, 1024, 1024, 0, 0, 0);

  // fixmean GEMV (needs wb alive)
  dim3 g3(8, 4);
  gemv_kernel<<<g3, 256, 0, stream>>>(mean_x, wb + 2097152, bv, fixmean);

  // scores[b] = q_b @ kc_b^T (compacted-causal tile-skip)
  dim3 g4(16, 16, 8);
  gemm_bt_kernel<1><<<g4, 256, 0, stream>>>(qb, nullptr, kcb, nullptr, nullptr, nullptr,
                                            sp, nullptr, nullptr, cntb,
                                            1024, 1024, 1024, 2048, 2097152, 2097152, 4194304);

  // compacted masked softmax (in place)
  dim3 g5(2048, 8);
  softmax_kernel<<<g5, 256, 0, stream>>>(sp, cntb);

  // out[b] = P_b @ Vc_b (K-limit roundup64(cnt))
  dim3 g6(8, 16, 8);
  gemm_bt_kernel<2><<<g6, 256, 0, stream>>>(sp, nullptr, vtc, nullptr, nullptr, nullptr,
                                            out, nullptr, nullptr, cntb,
                                            2048, 2048, 2048, 1024, 4194304, 2097152, 2097152);

  // degenerate (fully-masked) rows
  fixup_apply_kernel<<<g3, 256, 0, stream>>>(cntb, fixmean, out);
}